// Round 16
// baseline (2117.420 us; speedup 1.0000x reference)
//
#include <hip/hip_runtime.h>
#include <hip/hip_fp16.h>
#include <math.h>

#define NN 50000
#define NE 1600000
#define CC 128
#define FIN 64

typedef __attribute__((ext_vector_type(8))) _Float16 half8;   // f16 MFMA operand (4 VGPRs)
typedef __attribute__((ext_vector_type(2))) __fp16 fp16x2;    // pkrtz result type
typedef __attribute__((ext_vector_type(4))) float f32x4;

__device__ __forceinline__ f32x4 mfma16f(half8 a, half8 b, f32x4 c) {
  return __builtin_amdgcn_mfma_f32_16x16x32_f16(a, b, c, 0, 0, 0);
}

// silu via v_rcp_f32 (1 ULP)
__device__ __forceinline__ float silu_f(float x) {
  return x * __builtin_amdgcn_rcpf(1.0f + __expf(-x));
}
__device__ __forceinline__ float gelu_f(float x) { return 0.5f * x * (1.0f + erff(x * 0.7071067811865475f)); }

// pack two fp32 -> 2 f16 (RTZ), 1 instruction
__device__ __forceinline__ unsigned pkrtz(float a, float b) {
  fp16x2 h = __builtin_amdgcn_cvt_pkrtz(a, b);
  return *(unsigned*)&h;
}

__device__ __forceinline__ float hsum32(float v) {
  v += __shfl_xor(v, 16);
  v += __shfl_xor(v, 8);
  v += __shfl_xor(v, 4);
  v += __shfl_xor(v, 2);
  v += __shfl_xor(v, 1);
  return v;
}

// sum across 8 contiguous lanes
__device__ __forceinline__ float hsum8(float v) {
  v += __shfl_xor(v, 4);
  v += __shfl_xor(v, 2);
  v += __shfl_xor(v, 1);
  return v;
}

// ============================ dst-sort (counting sort via CSR) ==================================
__global__ __launch_bounds__(256)
void hist_kernel(const int* __restrict__ dst, int* __restrict__ cnt)
{
  const int i = blockIdx.x * 256 + threadIdx.x;
  if (i < NE) atomicAdd(&cnt[dst[i]], 1);
}

__global__ __launch_bounds__(1024)
void scan_kernel(const int* __restrict__ cnt, int* __restrict__ next)
{
  __shared__ int part[1024];
  const int tid = threadIdx.x;
  const int per = (NN + 1023) / 1024;   // 49
  const int base = tid * per;
  int s = 0;
  for (int i = 0; i < per; ++i) {
    const int n = base + i;
    if (n < NN) s += cnt[n];
  }
  part[tid] = s;
  __syncthreads();
  if (tid == 0) {
    int acc = 0;
    for (int i = 0; i < 1024; ++i) { const int t = part[i]; part[i] = acc; acc += t; }
  }
  __syncthreads();
  int off = part[tid];
  for (int i = 0; i < per; ++i) {
    const int n = base + i;
    if (n < NN) { next[n] = off; off += cnt[n]; }
  }
}

// writes the dst-sorted edge list directly as int2 (src, dst) — no perm indirection downstream
__global__ __launch_bounds__(256)
void slot_kernel(const int* __restrict__ src, const int* __restrict__ dst,
                 int* __restrict__ next, int2* __restrict__ sd)
{
  const int i = blockIdx.x * 256 + threadIdx.x;
  if (i < NE) {
    const int d = dst[i];
    sd[atomicAdd(&next[d], 1)] = make_int2(src[i], d);
  }
}

// ============================ weight split f16: Wh=f16(w), Wl=f16(w-Wh); [l][n][k] ==============
__global__ __launch_bounds__(256)
void wt_split(const float* __restrict__ W, __half* __restrict__ Wh, __half* __restrict__ Wl,
              const int K, const int layers, const int strideIn)
{
  const int gid = blockIdx.x * 256 + threadIdx.x;
  if (gid >= layers * 128 * K) return;
  const int l = gid / (128 * K);
  const int rem = gid - l * 128 * K;
  const int n = rem / K;
  const int k = rem - n * K;
  const float w = W[(size_t)l * strideIn + (size_t)k * 128 + n];
  const __half hi = __float2half(w);
  Wh[gid] = hi;
  Wl[gid] = __float2half(w - __half2float(hi));
}

// ============================ PQ precompute: P|Q = h @ [W1a|W1b] (+eb1 on P), fp16 out ==========
__global__ __launch_bounds__(256)
void pq_kernel(const __half* __restrict__ h_hi,
               const __half* __restrict__ W1h, const __half* __restrict__ W1l,
               const float* __restrict__ eb1, __half* __restrict__ PQ)
{
  __shared__ __align__(16) __half ah[32 * 128];   // 8 KB, swizzled: chunk c8 of row at c8^(row&15)
  const int tid = threadIdx.x;
  const int n0 = blockIdx.x * 32;
  {
    const int row = tid >> 3, sub = tid & 7;
    int n = n0 + row; if (n >= NN) n = NN - 1;
    #pragma unroll
    for (int t = 0; t < 2; ++t) {
      const int c8 = sub * 2 + t;
      const uint4 v = *(const uint4*)(h_hi + (size_t)n * CC + c8 * 8);
      *(uint4*)(ah + row * 128 + ((c8 ^ (row & 15)) * 8)) = v;
    }
  }
  __syncthreads();

  const int lane = tid & 63;
  const int li = lane & 15, quad = lane >> 4;
  const int wv = tid >> 6;
  const int c0 = wv * 32 + li, c1 = c0 + 16;

  f32x4 acc[2][4];  // [mi][Pc0, Pc1, Qc0, Qc1]
  {
    const float b0 = eb1[c0], b1 = eb1[c1];
    acc[0][0] = acc[1][0] = (f32x4){b0, b0, b0, b0};
    acc[0][1] = acc[1][1] = (f32x4){b1, b1, b1, b1};
    acc[0][2] = acc[1][2] = (f32x4){0, 0, 0, 0};
    acc[0][3] = acc[1][3] = (f32x4){0, 0, 0, 0};
  }
  const __half* bp[4] = { W1h + (size_t)c0 * 256, W1h + (size_t)c1 * 256,
                          W1h + (size_t)c0 * 256 + 128, W1h + (size_t)c1 * 256 + 128 };
  const __half* lp[4] = { W1l + (size_t)c0 * 256, W1l + (size_t)c1 * 256,
                          W1l + (size_t)c0 * 256 + 128, W1l + (size_t)c1 * 256 + 128 };
  #pragma unroll
  for (int ks = 0; ks < 4; ++ks) {
    const int ko = ks * 32 + quad * 8;
    half8 Bh[4], Bl[4];
    #pragma unroll
    for (int o = 0; o < 4; ++o) { Bh[o] = *(const half8*)(bp[o] + ko); Bl[o] = *(const half8*)(lp[o] + ko); }
    #pragma unroll
    for (int mi = 0; mi < 2; ++mi) {
      const half8 A = *(const half8*)(ah + (mi * 16 + li) * 128 + (((ks * 4 + quad) ^ li) * 8));
      #pragma unroll
      for (int o = 0; o < 4; ++o) {
        acc[mi][o] = mfma16f(A, Bh[o], acc[mi][o]);
        acc[mi][o] = mfma16f(A, Bl[o], acc[mi][o]);
      }
    }
  }
  const int cmap[4] = { c0, c1, 128 + c0, 128 + c1 };
  #pragma unroll
  for (int mi = 0; mi < 2; ++mi) {
    #pragma unroll
    for (int r = 0; r < 4; ++r) {
      const int n = n0 + mi * 16 + quad * 4 + r;
      if (n < NN) {
        __half* po = PQ + (size_t)n * 256;
        #pragma unroll
        for (int o = 0; o < 4; ++o) po[cmap[o]] = __float2half(acc[mi][o][r]);
      }
    }
  }
}

// ============================ edge kernel (R16: 256 edges/block, 16 waves) ======================
// dst-sorted int2 edge list (no perm chase). Wave wv: M-half mh=wv>>3 (8 M-tiles), N-tile nt=wv&7
// -> 64 MFMA/wave. Scan: 1024 threads = 128 ch x 8 groups of 32 rows. Numerics identical to R15.
template<int COORD>
__global__ __launch_bounds__(1024)
void edge_kernel(const int2* __restrict__ sd,
                 const __half* __restrict__ PQ, const float* __restrict__ xyz,
                 const float* __restrict__ w1rad,
                 const __half* __restrict__ W2h, const __half* __restrict__ W2l,
                 const float* __restrict__ eb2,
                 const __half* __restrict__ W3h, const __half* __restrict__ W3l,
                 const float* __restrict__ cb1, const float* __restrict__ cw2,
                 float* __restrict__ h_agg, float* __restrict__ x_agg)
{
  const int EPB = 256;
  __shared__ __align__(16) unsigned char smem[256 * 132 * 2];  // 67,584 B: ab / tbuf alias
  __shared__ int sidx[EPB], didx[EPB];
  __shared__ float radial[EPB];
  __shared__ float xdn[COORD ? EPB : 1][3];
  __shared__ float sx[COORD ? EPB : 1];
  __shared__ float cw2s[COORD ? 128 : 1];

  __half* ab = (__half*)smem;     // A buffer, swizzled: chunk c8 of row at (c8 ^ (row&15))
  __half* tbuf = (__half*)smem;   // scan buffer, plain stride 132 (alias, used after barrier)

  const int tid = threadIdx.x;
  const size_t ebase = (size_t)blockIdx.x * EPB;

  if (tid < EPB) {
    const int2 p = sd[ebase + tid];
    const int s = p.x, d = p.y;
    sidx[tid] = s; didx[tid] = d;
    const float* xs = xyz + (size_t)s * 3;
    const float* xd = xyz + (size_t)d * 3;
    const float dx = xs[0] - xd[0], dy = xs[1] - xd[1], dz = xs[2] - xd[2];
    const float r = dx * dx + dy * dy + dz * dz;
    radial[tid] = r;
    if (COORD) {
      const float inv = __builtin_amdgcn_rcpf(sqrtf(r) + 1e-30f);
      xdn[tid][0] = dx * inv; xdn[tid][1] = dy * inv; xdn[tid][2] = dz * inv;
    }
  }
  if (COORD && tid >= 256 && tid < 384) cw2s[tid - 256] = cw2[tid - 256];
  __syncthreads();

  // m1 = silu(P[src] + Q[dst] + r*w1rad): 4 threads/edge, 32 ch each; f16 pkrtz, swizzled b128
  {
    const int e = tid >> 2, q = tid & 3, c = q * 32;
    const float r = radial[e];
    const __half* prow = PQ + (size_t)sidx[e] * 256 + c;
    const __half* qrow = PQ + (size_t)didx[e] * 256 + 128 + c;
    #pragma unroll
    for (int i = 0; i < 4; ++i) {
      union { uint4 u; __half2 h2[4]; } pu, qu;
      pu.u = *(const uint4*)(prow + i * 8);
      qu.u = *(const uint4*)(qrow + i * 8);
      const float4 wa = *(const float4*)(w1rad + c + i * 8);
      const float4 wb = *(const float4*)(w1rad + c + i * 8 + 4);
      const float wf[8] = { wa.x, wa.y, wa.z, wa.w, wb.x, wb.y, wb.z, wb.w };
      float v[8];
      #pragma unroll
      for (int j = 0; j < 4; ++j) {
        const float2 p = __half22float2(pu.h2[j]);
        const float2 qq = __half22float2(qu.h2[j]);
        v[2 * j]     = silu_f(p.x + qq.x + r * wf[2 * j]);
        v[2 * j + 1] = silu_f(p.y + qq.y + r * wf[2 * j + 1]);
      }
      uint4 H;
      H.x = pkrtz(v[0], v[1]); H.y = pkrtz(v[2], v[3]);
      H.z = pkrtz(v[4], v[5]); H.w = pkrtz(v[6], v[7]);
      *(uint4*)(ab + e * 128 + (((q * 4 + i) ^ (e & 15)) * 8)) = H;
    }
  }
  __syncthreads();

  const int lane = tid & 63;
  const int li = lane & 15, quad = lane >> 4;
  const int wv = tid >> 6;            // 0..15
  const int mh = wv >> 3;             // M-half: rows mh*128 .. +128
  const int c0 = (wv & 7) * 16 + li;  // one 16-col N-tile per wave

  // ---- GEMM2: m1[256x128]@[128x128], f16 (A single, B hi/lo) -> silu (in regs) ---------------
  f32x4 mm[8];
  {
    const float b0 = eb2[c0];
    #pragma unroll
    for (int mi = 0; mi < 8; ++mi) mm[mi] = (f32x4){b0, b0, b0, b0};
  }
  {
    const __half* bh0 = W2h + (size_t)c0 * 128 + quad * 8;
    const __half* bl0 = W2l + (size_t)c0 * 128 + quad * 8;
    #pragma unroll
    for (int ks = 0; ks < 4; ++ks) {
      const half8 Bh0 = *(const half8*)(bh0 + ks * 32);
      const half8 Bl0 = *(const half8*)(bl0 + ks * 32);
      #pragma unroll
      for (int mi = 0; mi < 8; ++mi) {
        const int row = mh * 128 + mi * 16 + li;   // row&15 == li
        const half8 A = *(const half8*)(ab + row * 128 + (((ks * 4 + quad) ^ li) * 8));
        mm[mi] = mfma16f(A, Bh0, mm[mi]);
        mm[mi] = mfma16f(A, Bl0, mm[mi]);
      }
    }
  }
  #pragma unroll
  for (int mi = 0; mi < 8; ++mi) {
    #pragma unroll
    for (int r = 0; r < 4; ++r) mm[mi][r] = silu_f(mm[mi][r]);
  }
  __syncthreads();   // all GEMM2 A-reads of ab complete

  if (!COORD) {
    // ---- m f16 into tbuf (plain stride 132) -> per-channel segmented scan --------------------
    #pragma unroll
    for (int mi = 0; mi < 8; ++mi) {
      #pragma unroll
      for (int r = 0; r < 4; ++r)
        tbuf[(mh * 128 + mi * 16 + quad * 4 + r) * 132 + c0] = __float2half(mm[mi][r]);
    }
    __syncthreads();
    const int c = tid & 127, grp = tid >> 7;   // 8 groups of 32 rows
    const int j0 = grp * 32, j1 = j0 + 32;
    float ss = 0.0f;
    for (int j = j0; j < j1; ++j) {
      ss += __half2float(tbuf[j * 132 + c]);
      const int dj = didx[j];
      if (j == j1 - 1 || didx[j + 1] != dj) {
        atomicAdd(&h_agg[(size_t)dj * CC + c], ss);
        ss = 0.0f;
      }
    }
  } else {
    // ---- m f16 back into ab (swizzled, A of GEMM3) -------------------------------------------
    #pragma unroll
    for (int mi = 0; mi < 8; ++mi) {
      #pragma unroll
      for (int r = 0; r < 4; ++r) {
        const int row = mh * 128 + mi * 16 + quad * 4 + r;
        ab[row * 128 + (((c0 >> 3) ^ (row & 15)) * 8) + (c0 & 7)] = __float2half(mm[mi][r]);
      }
    }
    __syncthreads();
    // ---- segmented scan (reads swizzled ab) --------------------------------------------------
    {
      const int c = tid & 127, grp = tid >> 7;
      const int j0 = grp * 32, j1 = j0 + 32;
      float ss = 0.0f;
      for (int j = j0; j < j1; ++j) {
        ss += __half2float(ab[j * 128 + (((c >> 3) ^ (j & 15)) * 8) + (c & 7)]);
        const int dj = didx[j];
        if (j == j1 - 1 || didx[j + 1] != dj) {
          atomicAdd(&h_agg[(size_t)dj * CC + c], ss);
          ss = 0.0f;
        }
      }
    }
    // ---- GEMM3: m[256x128]@cw1, f16 -> silu -> t; cm = t . cw2; segmented x_agg flush --------
    f32x4 tt[8];
    {
      const float b0 = cb1[c0];
      #pragma unroll
      for (int mi = 0; mi < 8; ++mi) tt[mi] = (f32x4){b0, b0, b0, b0};
    }
    {
      const __half* bh0 = W3h + (size_t)c0 * 128 + quad * 8;
      const __half* bl0 = W3l + (size_t)c0 * 128 + quad * 8;
      #pragma unroll
      for (int ks = 0; ks < 4; ++ks) {
        const half8 Bh0 = *(const half8*)(bh0 + ks * 32);
        const half8 Bl0 = *(const half8*)(bl0 + ks * 32);
        #pragma unroll
        for (int mi = 0; mi < 8; ++mi) {
          const int row = mh * 128 + mi * 16 + li;
          const half8 A = *(const half8*)(ab + row * 128 + (((ks * 4 + quad) ^ li) * 8));
          tt[mi] = mfma16f(A, Bh0, tt[mi]);
          tt[mi] = mfma16f(A, Bl0, tt[mi]);
        }
      }
    }
    __syncthreads();   // scan + GEMM3 reads of ab done before tbuf alias
    #pragma unroll
    for (int mi = 0; mi < 8; ++mi) {
      #pragma unroll
      for (int r = 0; r < 4; ++r)
        tbuf[(mh * 128 + mi * 16 + quad * 4 + r) * 132 + c0] = __float2half(silu_f(tt[mi][r]));
    }
    __syncthreads();
    if (tid < EPB) {
      float ss = 0.0f;
      #pragma unroll 8
      for (int k = 0; k < CC; ++k) ss += __half2float(tbuf[tid * 132 + k]) * cw2s[k];
      sx[tid] = ss;
    }
    __syncthreads();
    if (tid < 24) {
      const int c = tid >> 3, grp = tid & 7;   // 3 ch x 8 groups of 32 rows
      const int j0 = grp * 32, j1 = j0 + 32;
      float a = 0.0f;
      for (int j = j0; j < j1; ++j) {
        a += sx[j] * xdn[j][c];
        const int dj = didx[j];
        if (j == j1 - 1 || didx[j + 1] != dj) {
          atomicAdd(&x_agg[(size_t)dj * 3 + c], a);
          a = 0.0f;
        }
      }
    }
  }
}

// ============================ node MFMA kernel (validated R14) ==================================
__global__ __launch_bounds__(256)
void node_mfma(const __half* __restrict__ h_hi, const __half* __restrict__ h_lo,
               const float* __restrict__ h_agg,
               const __half* __restrict__ NW1h, const __half* __restrict__ NW1l,
               const float* __restrict__ nb1,
               const __half* __restrict__ NW2h, const __half* __restrict__ NW2l,
               const float* __restrict__ nb2,
               __half* __restrict__ ho_hi, __half* __restrict__ ho_lo, const int post_ln,
               const float* __restrict__ lng, const float* __restrict__ lnb,
               const int do_coord, const float* __restrict__ xin,
               const float* __restrict__ x_agg, float* __restrict__ coord_out)
{
  __shared__ __align__(16) __half ab[32 * 256];
  __shared__ __align__(16) __half ab2[32 * 128];
  __shared__ float cbuf[32 * 132];

  const int tid = threadIdx.x;
  const int n0 = blockIdx.x * 32;

  {
    const int row = tid >> 3, q = tid & 7;
    int n = n0 + row; if (n >= NN) n = NN - 1;
    #pragma unroll
    for (int t = 0; t < 2; ++t) {
      const int c8 = q * 2 + t;
      const uint4 v = *(const uint4*)(h_hi + (size_t)n * CC + c8 * 8);
      *(uint4*)(ab + row * 256 + ((c8 ^ (row & 15)) * 8)) = v;
    }
    #pragma unroll
    for (int t = 0; t < 2; ++t) {
      const int c8 = 16 + q * 2 + t;
      const float4 a0 = *(const float4*)(h_agg + (size_t)n * CC + (q * 2 + t) * 8);
      const float4 a1 = *(const float4*)(h_agg + (size_t)n * CC + (q * 2 + t) * 8 + 4);
      uint4 H;
      H.x = pkrtz(a0.x, a0.y); H.y = pkrtz(a0.z, a0.w);
      H.z = pkrtz(a1.x, a1.y); H.w = pkrtz(a1.z, a1.w);
      *(uint4*)(ab + row * 256 + ((c8 ^ (row & 15)) * 8)) = H;
    }
  }
  if (do_coord && tid < 96) {
    const int n = n0 + tid / 3, d = tid % 3;
    if (n < NN)
      coord_out[(size_t)n * 3 + d] = xin[(size_t)n * 3 + d] + x_agg[(size_t)n * 3 + d];
  }
  __syncthreads();

  const int lane = tid & 63;
  const int li = lane & 15, quad = lane >> 4;
  const int wv = tid >> 6;

  f32x4 a1[2][2];
  {
    const float b0 = nb1[wv * 32 + li], b1 = nb1[wv * 32 + 16 + li];
    a1[0][0] = a1[1][0] = (f32x4){b0, b0, b0, b0};
    a1[0][1] = a1[1][1] = (f32x4){b1, b1, b1, b1};
  }
  {
    const __half* b0h = NW1h + (size_t)(wv * 32 + li) * 256 + quad * 8;
    const __half* b0l = NW1l + (size_t)(wv * 32 + li) * 256 + quad * 8;
    const __half* b1h = NW1h + (size_t)(wv * 32 + 16 + li) * 256 + quad * 8;
    const __half* b1l = NW1l + (size_t)(wv * 32 + 16 + li) * 256 + quad * 8;
    #pragma unroll
    for (int ks = 0; ks < 8; ++ks) {
      const half8 Bh0 = *(const half8*)(b0h + ks * 32);
      const half8 Bl0 = *(const half8*)(b0l + ks * 32);
      const half8 Bh1 = *(const half8*)(b1h + ks * 32);
      const half8 Bl1 = *(const half8*)(b1l + ks * 32);
      #pragma unroll
      for (int mi = 0; mi < 2; ++mi) {
        const half8 A = *(const half8*)(ab + (mi * 16 + li) * 256 + (((ks * 4 + quad) ^ li) * 8));
        a1[mi][0] = mfma16f(A, Bh0, a1[mi][0]);
        a1[mi][0] = mfma16f(A, Bl0, a1[mi][0]);
        a1[mi][1] = mfma16f(A, Bh1, a1[mi][1]);
        a1[mi][1] = mfma16f(A, Bl1, a1[mi][1]);
      }
    }
  }
  #pragma unroll
  for (int mi = 0; mi < 2; ++mi) {
    #pragma unroll
    for (int nc = 0; nc < 2; ++nc) {
      const int col = wv * 32 + nc * 16 + li;
      #pragma unroll
      for (int r = 0; r < 4; ++r) {
        const int row = mi * 16 + quad * 4 + r;
        ab2[row * 128 + (((col >> 3) ^ (row & 15)) * 8) + (col & 7)] =
            __float2half(silu_f(a1[mi][nc][r]));
      }
    }
  }
  __syncthreads();

  f32x4 a2[2][2];
  {
    const float b0 = nb2[wv * 32 + li], b1 = nb2[wv * 32 + 16 + li];
    a2[0][0] = a2[1][0] = (f32x4){b0, b0, b0, b0};
    a2[0][1] = a2[1][1] = (f32x4){b1, b1, b1, b1};
  }
  {
    const __half* b0h = NW2h + (size_t)(wv * 32 + li) * 128 + quad * 8;
    const __half* b0l = NW2l + (size_t)(wv * 32 + li) * 128 + quad * 8;
    const __half* b1h = NW2h + (size_t)(wv * 32 + 16 + li) * 128 + quad * 8;
    const __half* b1l = NW2l + (size_t)(wv * 32 + 16 + li) * 128 + quad * 8;
    #pragma unroll
    for (int ks = 0; ks < 4; ++ks) {
      const half8 Bh0 = *(const half8*)(b0h + ks * 32);
      const half8 Bl0 = *(const half8*)(b0l + ks * 32);
      const half8 Bh1 = *(const half8*)(b1h + ks * 32);
      const half8 Bl1 = *(const half8*)(b1l + ks * 32);
      #pragma unroll
      for (int mi = 0; mi < 2; ++mi) {
        const half8 A = *(const half8*)(ab2 + (mi * 16 + li) * 128 + (((ks * 4 + quad) ^ li) * 8));
        a2[mi][0] = mfma16f(A, Bh0, a2[mi][0]);
        a2[mi][0] = mfma16f(A, Bl0, a2[mi][0]);
        a2[mi][1] = mfma16f(A, Bh1, a2[mi][1]);
        a2[mi][1] = mfma16f(A, Bl1, a2[mi][1]);
      }
    }
  }
  #pragma unroll
  for (int mi = 0; mi < 2; ++mi) {
    #pragma unroll
    for (int nc = 0; nc < 2; ++nc) {
      const int col = wv * 32 + nc * 16 + li;
      #pragma unroll
      for (int r = 0; r < 4; ++r)
        cbuf[(mi * 16 + quad * 4 + r) * 132 + col] = a2[mi][nc][r];
    }
  }
  __syncthreads();

  {
    const int row = tid >> 3, q = tid & 7;
    const int n = n0 + row;
    float v[16];
    #pragma unroll
    for (int i = 0; i < 16; ++i) v[i] = cbuf[row * 132 + q * 16 + i];
    if (post_ln) {
      float s = 0.0f;
      #pragma unroll
      for (int i = 0; i < 16; ++i) { v[i] = gelu_f(v[i]); s += v[i]; }
      const float mu = hsum8(s) * (1.0f / 128.0f);
      float vs = 0.0f;
      #pragma unroll
      for (int i = 0; i < 16; ++i) { v[i] -= mu; vs += v[i] * v[i]; }
      const float rs = rsqrtf(hsum8(vs) * (1.0f / 128.0f) + 1e-5f);
      #pragma unroll
      for (int i = 0; i < 16; ++i)
        v[i] = v[i] * rs * lng[q * 16 + i] + lnb[q * 16 + i];
    }
    if (n < NN) {
      __half h[16], l[16];
      #pragma unroll
      for (int i = 0; i < 16; ++i) {
        h[i] = __float2half(v[i]);
        l[i] = __float2half(v[i] - __half2float(h[i]));
      }
      #pragma unroll
      for (int t = 0; t < 2; ++t) {
        *(uint4*)(ho_hi + (size_t)n * CC + q * 16 + t * 8) = *(uint4*)(h + t * 8);
        *(uint4*)(ho_lo + (size_t)n * CC + q * 16 + t * 8) = *(uint4*)(l + t * 8);
      }
    }
  }
}

// ============================ fp32 node-side kernels (embed / out) ==============================
template<int K, int ROWS>
__device__ __forceinline__ void mm_tile(const float* __restrict__ fb, const int fstride,
                                        const float* __restrict__ W, const float* __restrict__ bias,
                                        const int c0, const int r0, float (&acc)[ROWS][4])
{
  const float4 b = *(const float4*)(bias + c0);
  #pragma unroll
  for (int i = 0; i < ROWS; ++i) { acc[i][0] = b.x; acc[i][1] = b.y; acc[i][2] = b.z; acc[i][3] = b.w; }
  #pragma unroll 2
  for (int k = 0; k < K; k += 4) {
    const float4 w0 = *(const float4*)(W + (size_t)(k + 0) * CC + c0);
    const float4 w1 = *(const float4*)(W + (size_t)(k + 1) * CC + c0);
    const float4 w2 = *(const float4*)(W + (size_t)(k + 2) * CC + c0);
    const float4 w3 = *(const float4*)(W + (size_t)(k + 3) * CC + c0);
    #pragma unroll
    for (int i = 0; i < ROWS; ++i) {
      const float4 f = *(const float4*)(fb + (r0 + i) * fstride + k);
      acc[i][0] += f.x * w0.x + f.y * w1.x + f.z * w2.x + f.w * w3.x;
      acc[i][1] += f.x * w0.y + f.y * w1.y + f.z * w2.y + f.w * w3.y;
      acc[i][2] += f.x * w0.z + f.y * w1.z + f.z * w2.z + f.w * w3.z;
      acc[i][3] += f.x * w0.w + f.y * w1.w + f.z * w2.w + f.w * w3.w;
    }
  }
}

__device__ __forceinline__ void ln_then_gelu(float (&v)[4], const float* __restrict__ g,
                                             const float* __restrict__ b, const int c0)
{
  const float mu = hsum32(v[0] + v[1] + v[2] + v[3]) * (1.0f / 128.0f);
  const float d0 = v[0] - mu, d1 = v[1] - mu, d2 = v[2] - mu, d3 = v[3] - mu;
  const float var = hsum32(d0 * d0 + d1 * d1 + d2 * d2 + d3 * d3) * (1.0f / 128.0f);
  const float rs = rsqrtf(var + 1e-5f);
  const float4 gv = *(const float4*)(g + c0);
  const float4 bv = *(const float4*)(b + c0);
  v[0] = gelu_f(d0 * rs * gv.x + bv.x);
  v[1] = gelu_f(d1 * rs * gv.y + bv.y);
  v[2] = gelu_f(d2 * rs * gv.z + bv.z);
  v[3] = gelu_f(d3 * rs * gv.w + bv.w);
}

__device__ __forceinline__ void store_hilo4(__half* __restrict__ hi, __half* __restrict__ lo,
                                            const float v0, const float v1,
                                            const float v2, const float v3)
{
  __half h[4], l[4];
  h[0] = __float2half(v0); h[1] = __float2half(v1); h[2] = __float2half(v2); h[3] = __float2half(v3);
  l[0] = __float2half(v0 - __half2float(h[0]));
  l[1] = __float2half(v1 - __half2float(h[1]));
  l[2] = __float2half(v2 - __half2float(h[2]));
  l[3] = __float2half(v3 - __half2float(h[3]));
  *(ushort4*)hi = *(ushort4*)h;
  *(ushort4*)lo = *(ushort4*)l;
}

__global__ __launch_bounds__(256)
void embed_kernel(const float* __restrict__ na,
                  const float* __restrict__ w1, const float* __restrict__ b1,
                  const float* __restrict__ g1, const float* __restrict__ be1,
                  const float* __restrict__ w2, const float* __restrict__ b2,
                  const float* __restrict__ g2, const float* __restrict__ be2,
                  __half* __restrict__ ho_hi, __half* __restrict__ ho_lo)
{
  const int AS = 68, MS = 132;
  __shared__ float ain[16 * AS];
  __shared__ float hb[16 * MS];
  const int tid = threadIdx.x;
  const size_t n0 = (size_t)blockIdx.x * 16;
  {
    const int n = tid >> 4, q = tid & 15;
    *(float4*)(ain + n * AS + q * 4) = *(const float4*)(na + (n0 + n) * FIN + q * 4);
  }
  __syncthreads();
  const int cg = tid & 31, ng = tid >> 5;
  const int c0 = cg * 4, m0 = ng * 2;
  float acc[2][4];
  mm_tile<64, 2>(ain, AS, w1, b1, c0, m0, acc);
  #pragma unroll
  for (int i = 0; i < 2; ++i) {
    ln_then_gelu(acc[i], g1, be1, c0);
    *(float4*)(hb + (m0 + i) * MS + c0) = make_float4(acc[i][0], acc[i][1], acc[i][2], acc[i][3]);
  }
  __syncthreads();
  float acc2[2][4];
  mm_tile<128, 2>(hb, MS, w2, b2, c0, m0, acc2);
  #pragma unroll
  for (int i = 0; i < 2; ++i) {
    ln_then_gelu(acc2[i], g2, be2, c0);
    store_hilo4(ho_hi + (n0 + m0 + i) * CC + c0, ho_lo + (n0 + m0 + i) * CC + c0,
                acc2[i][0], acc2[i][1], acc2[i][2], acc2[i][3]);
  }
}

__global__ __launch_bounds__(192)
void out_kernel(const __half* __restrict__ h_hi, const __half* __restrict__ h_lo,
                const float* __restrict__ w, const float* __restrict__ b,
                float* __restrict__ out)
{
  const int gid = blockIdx.x * 192 + threadIdx.x;
  if (gid >= NN * 3) return;
  const int n = gid / 3, j = gid % 3;
  float acc = b[j];
  const __half* hh = h_hi + (size_t)n * CC;
  const __half* hl = h_lo + (size_t)n * CC;
  #pragma unroll 4
  for (int k = 0; k < CC; ++k) acc += (__half2float(hh[k]) + __half2float(hl[k])) * w[k * 3 + j];
  out[gid] = acc;
}

// ================================================================================================
extern "C" void kernel_launch(void* const* d_in, const int* in_sizes, int n_in,
                              void* d_out, int out_size, void* d_ws, size_t ws_size,
                              hipStream_t stream)
{
  (void)in_sizes; (void)n_in; (void)out_size; (void)ws_size;
  const int*   src       = (const int*)d_in[0];
  const int*   dst       = (const int*)d_in[1];
  const float* node_attr = (const float*)d_in[2];
  const float* xyz       = (const float*)d_in[3];
  const float* emb_w1    = (const float*)d_in[4];
  const float* emb_b1    = (const float*)d_in[5];
  const float* ln1_g     = (const float*)d_in[6];
  const float* ln1_b     = (const float*)d_in[7];
  const float* emb_w2    = (const float*)d_in[8];
  const float* emb_b2    = (const float*)d_in[9];
  const float* ln2_g     = (const float*)d_in[10];
  const float* ln2_b     = (const float*)d_in[11];
  const float* e_w1      = (const float*)d_in[12];
  const float* e_b1      = (const float*)d_in[13];
  const float* e_w2      = (const float*)d_in[14];
  const float* e_b2      = (const float*)d_in[15];
  const float* n_w1      = (const float*)d_in[16];
  const float* n_b1      = (const float*)d_in[17];
  const float* n_w2      = (const float*)d_in[18];
  const float* n_b2      = (const float*)d_in[19];
  const float* c_w1      = (const float*)d_in[20];
  const float* c_b1      = (const float*)d_in[21];
  const float* c_w2      = (const float*)d_in[22];
  const float* dec_ln_g  = (const float*)d_in[23];
  const float* dec_ln_b  = (const float*)d_in[24];
  const float* out_w     = (const float*)d_in[25];
  const float* out_b     = (const float*)d_in[26];

  // workspace layout (~95 MB total)
  char* wsb = (char*)d_ws;
  float*  h_agg = (float*)wsb;                      wsb += (size_t)NN * CC * 4;   // 25.6 MB
  __half* PQ    = (__half*)wsb;                     wsb += (size_t)NN * 256 * 2;  // 25.6 MB
  float*  x_agg = (float*)wsb;                      wsb += (size_t)NN * 3 * 4;
  float*  coord = (float*)wsb;                      wsb += (size_t)NN * 3 * 4;
  __half* h_hi  = (__half*)wsb;                     wsb += (size_t)NN * CC * 2;   // 12.8 MB
  __half* h_lo  = (__half*)wsb;                     wsb += (size_t)NN * CC * 2;   // 12.8 MB
  __half* W1h   = (__half*)wsb;                     wsb += (size_t)3 * 128 * 256 * 2;
  __half* W1l   = (__half*)wsb;                     wsb += (size_t)3 * 128 * 256 * 2;
  __half* W2h   = (__half*)wsb;                     wsb += (size_t)3 * 128 * 128 * 2;
  __half* W2l   = (__half*)wsb;                     wsb += (size_t)3 * 128 * 128 * 2;
  __half* W3h   = (__half*)wsb;                     wsb += (size_t)128 * 128 * 2;
  __half* W3l   = (__half*)wsb;                     wsb += (size_t)128 * 128 * 2;
  __half* NW1h  = (__half*)wsb;                     wsb += (size_t)3 * 128 * 256 * 2;
  __half* NW1l  = (__half*)wsb;                     wsb += (size_t)3 * 128 * 256 * 2;
  __half* NW2h  = (__half*)wsb;                     wsb += (size_t)3 * 128 * 128 * 2;
  __half* NW2l  = (__half*)wsb;                     wsb += (size_t)3 * 128 * 128 * 2;
  int2*   sdA   = (int2*)wsb;                       wsb += (size_t)NE * 8;        // 12.8 MB
  int*    cnt   = (int*)wsb;                        wsb += (size_t)NN * 4;
  int*    nextA = (int*)wsb;                        wsb += (size_t)NN * 4;
  float*  out   = (float*)d_out;

  const int NGRID = NN / 16;            // 3125 (embed)
  const int N32GRID = (NN + 31) / 32;   // 1563 (node_mfma / pq)
  const int EGRID = NE / 256;           // 6250 (R16: 256 edges/block)

  // weight split (tiny)
  wt_split<<<(3 * 128 * 256 + 255) / 256, 256, 0, stream>>>(e_w1, W1h, W1l, 256, 3, 257 * 128);
  wt_split<<<(3 * 128 * 128 + 255) / 256, 256, 0, stream>>>(e_w2, W2h, W2l, 128, 3, 128 * 128);
  wt_split<<<(128 * 128 + 255) / 256, 256, 0, stream>>>(c_w1 + (size_t)128 * 128, W3h, W3l, 128, 1, 0);
  wt_split<<<(3 * 128 * 256 + 255) / 256, 256, 0, stream>>>(n_w1, NW1h, NW1l, 256, 3, 256 * 128);
  wt_split<<<(3 * 128 * 128 + 255) / 256, 256, 0, stream>>>(n_w2, NW2h, NW2l, 128, 3, 128 * 128);

  // dst-sort (counting sort) once per call; sorted (src,dst) pairs written directly
  (void)hipMemsetAsync(cnt, 0, (size_t)NN * 4, stream);
  hist_kernel<<<(NE + 255) / 256, 256, 0, stream>>>(dst, cnt);
  scan_kernel<<<1, 1024, 0, stream>>>(cnt, nextA);
  slot_kernel<<<(NE + 255) / 256, 256, 0, stream>>>(src, dst, nextA, sdA);

  embed_kernel<<<NGRID, 256, 0, stream>>>(node_attr, emb_w1, emb_b1, ln1_g, ln1_b,
                                          emb_w2, emb_b2, ln2_g, ln2_b, h_hi, h_lo);

  // ---- layer 0 (encoder): coord output discarded
  (void)hipMemsetAsync(h_agg, 0, (size_t)NN * CC * 4, stream);
  pq_kernel<<<N32GRID, 256, 0, stream>>>(h_hi, W1h, W1l, e_b1, PQ);
  edge_kernel<0><<<EGRID, 1024, 0, stream>>>(sdA, PQ, xyz,
      e_w1 + (size_t)256 * CC, W2h, W2l, e_b2, W3h, W3l, c_b1, c_w2, h_agg, x_agg);
  node_mfma<<<N32GRID, 256, 0, stream>>>(h_hi, h_lo, h_agg,
      NW1h, NW1l, n_b1, NW2h, NW2l, n_b2,
      h_hi, h_lo, 0, dec_ln_g, dec_ln_b, 0, xyz, x_agg, coord);

  // ---- layer 1 (decoder #1): coord MLP active; input coords = xyz
  (void)hipMemsetAsync(h_agg, 0, (size_t)NN * CC * 4, stream);
  (void)hipMemsetAsync(x_agg, 0, (size_t)NN * 3 * 4, stream);
  pq_kernel<<<N32GRID, 256, 0, stream>>>(h_hi, W1h + (size_t)128 * 256,
      W1l + (size_t)128 * 256, e_b1 + CC, PQ);
  edge_kernel<1><<<EGRID, 1024, 0, stream>>>(sdA, PQ, xyz,
      e_w1 + (size_t)(257 + 256) * CC,
      W2h + (size_t)128 * 128, W2l + (size_t)128 * 128, e_b2 + CC,
      W3h, W3l, c_b1 + CC, c_w2 + CC, h_agg, x_agg);
  node_mfma<<<N32GRID, 256, 0, stream>>>(h_hi, h_lo, h_agg,
      NW1h + (size_t)128 * 256, NW1l + (size_t)128 * 256, n_b1 + CC,
      NW2h + (size_t)128 * 128, NW2l + (size_t)128 * 128, n_b2 + CC,
      h_hi, h_lo, 1, dec_ln_g, dec_ln_b, 1, xyz, x_agg, coord);

  // ---- layer 2 (decoder #2): coord output discarded; input coords = coord
  (void)hipMemsetAsync(h_agg, 0, (size_t)NN * CC * 4, stream);
  pq_kernel<<<N32GRID, 256, 0, stream>>>(h_hi, W1h + (size_t)2 * 128 * 256,
      W1l + (size_t)2 * 128 * 256, e_b1 + 2 * CC, PQ);
  edge_kernel<0><<<EGRID, 1024, 0, stream>>>(sdA, PQ, coord,
      e_w1 + (size_t)(2 * 257 + 256) * CC,
      W2h + (size_t)2 * 128 * 128, W2l + (size_t)2 * 128 * 128, e_b2 + 2 * CC,
      W3h, W3l, c_b1, c_w2, h_agg, x_agg);
  node_mfma<<<N32GRID, 256, 0, stream>>>(h_hi, h_lo, h_agg,
      NW1h + (size_t)2 * 128 * 256, NW1l + (size_t)2 * 128 * 256, n_b1 + 2 * CC,
      NW2h + (size_t)2 * 128 * 128, NW2l + (size_t)2 * 128 * 128, n_b2 + 2 * CC,
      h_hi, h_lo, 1, dec_ln_g, dec_ln_b, 0, xyz, x_agg, coord);

  out_kernel<<<(NN * 3 + 191) / 192, 192, 0, stream>>>(h_hi, h_lo, out_w, out_b, out);
}

// Round 17
// 1722.842 us; speedup vs baseline: 1.2290x; 1.2290x over previous
//
#include <hip/hip_runtime.h>
#include <hip/hip_fp16.h>
#include <math.h>

#define NN 50000
#define NE 1600000
#define CC 128
#define FIN 64

typedef __attribute__((ext_vector_type(8))) _Float16 half8;   // f16 MFMA operand (4 VGPRs)
typedef __attribute__((ext_vector_type(2))) __fp16 fp16x2;    // pkrtz result type
typedef __attribute__((ext_vector_type(4))) float f32x4;

__device__ __forceinline__ f32x4 mfma16f(half8 a, half8 b, f32x4 c) {
  return __builtin_amdgcn_mfma_f32_16x16x32_f16(a, b, c, 0, 0, 0);
}

// silu via v_rcp_f32 (1 ULP)
__device__ __forceinline__ float silu_f(float x) {
  return x * __builtin_amdgcn_rcpf(1.0f + __expf(-x));
}
__device__ __forceinline__ float gelu_f(float x) { return 0.5f * x * (1.0f + erff(x * 0.7071067811865475f)); }

// pack two fp32 -> 2 f16 (RTZ), 1 instruction
__device__ __forceinline__ unsigned pkrtz(float a, float b) {
  fp16x2 h = __builtin_amdgcn_cvt_pkrtz(a, b);
  return *(unsigned*)&h;
}

__device__ __forceinline__ float hsum32(float v) {
  v += __shfl_xor(v, 16);
  v += __shfl_xor(v, 8);
  v += __shfl_xor(v, 4);
  v += __shfl_xor(v, 2);
  v += __shfl_xor(v, 1);
  return v;
}

// sum across 8 contiguous lanes
__device__ __forceinline__ float hsum8(float v) {
  v += __shfl_xor(v, 4);
  v += __shfl_xor(v, 2);
  v += __shfl_xor(v, 1);
  return v;
}

// ============================ dst-sort (counting sort via CSR) ==================================
__global__ __launch_bounds__(256)
void hist_kernel(const int* __restrict__ dst, int* __restrict__ cnt)
{
  const int i = blockIdx.x * 256 + threadIdx.x;
  if (i < NE) atomicAdd(&cnt[dst[i]], 1);
}

__global__ __launch_bounds__(1024)
void scan_kernel(const int* __restrict__ cnt, int* __restrict__ next)
{
  __shared__ int part[1024];
  const int tid = threadIdx.x;
  const int per = (NN + 1023) / 1024;   // 49
  const int base = tid * per;
  int s = 0;
  for (int i = 0; i < per; ++i) {
    const int n = base + i;
    if (n < NN) s += cnt[n];
  }
  part[tid] = s;
  __syncthreads();
  if (tid == 0) {
    int acc = 0;
    for (int i = 0; i < 1024; ++i) { const int t = part[i]; part[i] = acc; acc += t; }
  }
  __syncthreads();
  int off = part[tid];
  for (int i = 0; i < per; ++i) {
    const int n = base + i;
    if (n < NN) { next[n] = off; off += cnt[n]; }
  }
}

// writes the dst-sorted edge list directly as int2 (src, dst) — no perm indirection downstream
__global__ __launch_bounds__(256)
void slot_kernel(const int* __restrict__ src, const int* __restrict__ dst,
                 int* __restrict__ next, int2* __restrict__ sd)
{
  const int i = blockIdx.x * 256 + threadIdx.x;
  if (i < NE) {
    const int d = dst[i];
    sd[atomicAdd(&next[d], 1)] = make_int2(src[i], d);
  }
}

// ============================ weight split f16: Wh=f16(w), Wl=f16(w-Wh); [l][n][k] ==============
__global__ __launch_bounds__(256)
void wt_split(const float* __restrict__ W, __half* __restrict__ Wh, __half* __restrict__ Wl,
              const int K, const int layers, const int strideIn)
{
  const int gid = blockIdx.x * 256 + threadIdx.x;
  if (gid >= layers * 128 * K) return;
  const int l = gid / (128 * K);
  const int rem = gid - l * 128 * K;
  const int n = rem / K;
  const int k = rem - n * K;
  const float w = W[(size_t)l * strideIn + (size_t)k * 128 + n];
  const __half hi = __float2half(w);
  Wh[gid] = hi;
  Wl[gid] = __float2half(w - __half2float(hi));
}

// ============================ PQ precompute: P|Q = h @ [W1a|W1b] (+eb1 on P), fp16 out ==========
__global__ __launch_bounds__(256)
void pq_kernel(const __half* __restrict__ h_hi,
               const __half* __restrict__ W1h, const __half* __restrict__ W1l,
               const float* __restrict__ eb1, __half* __restrict__ PQ)
{
  __shared__ __align__(16) __half ah[32 * 128];   // 8 KB, swizzled: chunk c8 of row at c8^(row&15)
  const int tid = threadIdx.x;
  const int n0 = blockIdx.x * 32;
  {
    const int row = tid >> 3, sub = tid & 7;
    int n = n0 + row; if (n >= NN) n = NN - 1;
    #pragma unroll
    for (int t = 0; t < 2; ++t) {
      const int c8 = sub * 2 + t;
      const uint4 v = *(const uint4*)(h_hi + (size_t)n * CC + c8 * 8);
      *(uint4*)(ah + row * 128 + ((c8 ^ (row & 15)) * 8)) = v;
    }
  }
  __syncthreads();

  const int lane = tid & 63;
  const int li = lane & 15, quad = lane >> 4;
  const int wv = tid >> 6;
  const int c0 = wv * 32 + li, c1 = c0 + 16;

  f32x4 acc[2][4];  // [mi][Pc0, Pc1, Qc0, Qc1]
  {
    const float b0 = eb1[c0], b1 = eb1[c1];
    acc[0][0] = acc[1][0] = (f32x4){b0, b0, b0, b0};
    acc[0][1] = acc[1][1] = (f32x4){b1, b1, b1, b1};
    acc[0][2] = acc[1][2] = (f32x4){0, 0, 0, 0};
    acc[0][3] = acc[1][3] = (f32x4){0, 0, 0, 0};
  }
  const __half* bp[4] = { W1h + (size_t)c0 * 256, W1h + (size_t)c1 * 256,
                          W1h + (size_t)c0 * 256 + 128, W1h + (size_t)c1 * 256 + 128 };
  const __half* lp[4] = { W1l + (size_t)c0 * 256, W1l + (size_t)c1 * 256,
                          W1l + (size_t)c0 * 256 + 128, W1l + (size_t)c1 * 256 + 128 };
  #pragma unroll
  for (int ks = 0; ks < 4; ++ks) {
    const int ko = ks * 32 + quad * 8;
    half8 Bh[4], Bl[4];
    #pragma unroll
    for (int o = 0; o < 4; ++o) { Bh[o] = *(const half8*)(bp[o] + ko); Bl[o] = *(const half8*)(lp[o] + ko); }
    #pragma unroll
    for (int mi = 0; mi < 2; ++mi) {
      const half8 A = *(const half8*)(ah + (mi * 16 + li) * 128 + (((ks * 4 + quad) ^ li) * 8));
      #pragma unroll
      for (int o = 0; o < 4; ++o) {
        acc[mi][o] = mfma16f(A, Bh[o], acc[mi][o]);
        acc[mi][o] = mfma16f(A, Bl[o], acc[mi][o]);
      }
    }
  }
  const int cmap[4] = { c0, c1, 128 + c0, 128 + c1 };
  #pragma unroll
  for (int mi = 0; mi < 2; ++mi) {
    #pragma unroll
    for (int r = 0; r < 4; ++r) {
      const int n = n0 + mi * 16 + quad * 4 + r;
      if (n < NN) {
        __half* po = PQ + (size_t)n * 256;
        #pragma unroll
        for (int o = 0; o < 4; ++o) po[cmap[o]] = __float2half(acc[mi][o][r]);
      }
    }
  }
}

// ============================ edge kernel (R17 = R15 geometry + int2 edge list) =================
// 128 edges/block, 8 waves, dst-sorted int2 list. Wave wv owns one 16-col N-tile, all 8 M-tiles.
// Scan: 512 threads = 128 ch x 4 groups of 32 rows. Numerics identical to R15.
template<int COORD>
__global__ __launch_bounds__(512)
void edge_kernel(const int2* __restrict__ sd,
                 const __half* __restrict__ PQ, const float* __restrict__ xyz,
                 const float* __restrict__ w1rad,
                 const __half* __restrict__ W2h, const __half* __restrict__ W2l,
                 const float* __restrict__ eb2,
                 const __half* __restrict__ W3h, const __half* __restrict__ W3l,
                 const float* __restrict__ cb1, const float* __restrict__ cw2,
                 float* __restrict__ h_agg, float* __restrict__ x_agg)
{
  const int EPB = 128;
  __shared__ __align__(16) unsigned char smem[128 * 132 * 2];  // 33,792 B: ab / tbuf alias
  __shared__ int sidx[EPB], didx[EPB];
  __shared__ float radial[EPB];
  __shared__ float xdn[COORD ? EPB : 1][3];
  __shared__ float sx[COORD ? EPB : 1];
  __shared__ float cw2s[COORD ? 128 : 1];

  __half* ab = (__half*)smem;     // A buffer, swizzled: chunk c8 of row at (c8 ^ (row&15))
  __half* tbuf = (__half*)smem;   // scan buffer, plain stride 132 (alias, used after barrier)

  const int tid = threadIdx.x;
  const size_t ebase = (size_t)blockIdx.x * EPB;

  if (tid < EPB) {
    const int2 p = sd[ebase + tid];
    const int s = p.x, d = p.y;
    sidx[tid] = s; didx[tid] = d;
    const float* xs = xyz + (size_t)s * 3;
    const float* xd = xyz + (size_t)d * 3;
    const float dx = xs[0] - xd[0], dy = xs[1] - xd[1], dz = xs[2] - xd[2];
    const float r = dx * dx + dy * dy + dz * dz;
    radial[tid] = r;
    if (COORD) {
      const float inv = __builtin_amdgcn_rcpf(sqrtf(r) + 1e-30f);
      xdn[tid][0] = dx * inv; xdn[tid][1] = dy * inv; xdn[tid][2] = dz * inv;
    }
  }
  if (COORD && tid >= 128 && tid < 256) cw2s[tid - 128] = cw2[tid - 128];
  __syncthreads();

  // m1 = silu(P[src] + Q[dst] + r*w1rad): 4 threads/edge, 32 ch each; f16 pkrtz, swizzled b128
  {
    const int e = tid >> 2, q = tid & 3, c = q * 32;
    const float r = radial[e];
    const __half* prow = PQ + (size_t)sidx[e] * 256 + c;
    const __half* qrow = PQ + (size_t)didx[e] * 256 + 128 + c;
    #pragma unroll
    for (int i = 0; i < 4; ++i) {
      union { uint4 u; __half2 h2[4]; } pu, qu;
      pu.u = *(const uint4*)(prow + i * 8);
      qu.u = *(const uint4*)(qrow + i * 8);
      const float4 wa = *(const float4*)(w1rad + c + i * 8);
      const float4 wb = *(const float4*)(w1rad + c + i * 8 + 4);
      const float wf[8] = { wa.x, wa.y, wa.z, wa.w, wb.x, wb.y, wb.z, wb.w };
      float v[8];
      #pragma unroll
      for (int j = 0; j < 4; ++j) {
        const float2 p = __half22float2(pu.h2[j]);
        const float2 qq = __half22float2(qu.h2[j]);
        v[2 * j]     = silu_f(p.x + qq.x + r * wf[2 * j]);
        v[2 * j + 1] = silu_f(p.y + qq.y + r * wf[2 * j + 1]);
      }
      uint4 H;
      H.x = pkrtz(v[0], v[1]); H.y = pkrtz(v[2], v[3]);
      H.z = pkrtz(v[4], v[5]); H.w = pkrtz(v[6], v[7]);
      *(uint4*)(ab + e * 128 + (((q * 4 + i) ^ (e & 15)) * 8)) = H;
    }
  }
  __syncthreads();

  const int lane = tid & 63;
  const int li = lane & 15, quad = lane >> 4;
  const int wv = tid >> 6;            // 0..7
  const int c0 = wv * 16 + li;        // one 16-col N-tile per wave

  // ---- GEMM2: m1[128x128]@[128x128], f16 (A single, B hi/lo) -> silu (in regs) ---------------
  f32x4 mm[8];
  {
    const float b0 = eb2[c0];
    #pragma unroll
    for (int mi = 0; mi < 8; ++mi) mm[mi] = (f32x4){b0, b0, b0, b0};
  }
  {
    const __half* bh0 = W2h + (size_t)c0 * 128 + quad * 8;
    const __half* bl0 = W2l + (size_t)c0 * 128 + quad * 8;
    #pragma unroll
    for (int ks = 0; ks < 4; ++ks) {
      const half8 Bh0 = *(const half8*)(bh0 + ks * 32);
      const half8 Bl0 = *(const half8*)(bl0 + ks * 32);
      #pragma unroll
      for (int mi = 0; mi < 8; ++mi) {
        const half8 A = *(const half8*)(ab + (mi * 16 + li) * 128 + (((ks * 4 + quad) ^ li) * 8));
        mm[mi] = mfma16f(A, Bh0, mm[mi]);
        mm[mi] = mfma16f(A, Bl0, mm[mi]);
      }
    }
  }
  #pragma unroll
  for (int mi = 0; mi < 8; ++mi) {
    #pragma unroll
    for (int r = 0; r < 4; ++r) mm[mi][r] = silu_f(mm[mi][r]);
  }
  __syncthreads();   // all GEMM2 A-reads of ab complete

  if (!COORD) {
    // ---- m f16 into tbuf (plain stride 132) -> per-channel segmented scan --------------------
    #pragma unroll
    for (int mi = 0; mi < 8; ++mi) {
      #pragma unroll
      for (int r = 0; r < 4; ++r)
        tbuf[(mi * 16 + quad * 4 + r) * 132 + c0] = __float2half(mm[mi][r]);
    }
    __syncthreads();
    const int c = tid & 127, grp = tid >> 7;   // 4 groups of 32 rows
    const int j0 = grp * 32, j1 = j0 + 32;
    float ss = 0.0f;
    for (int j = j0; j < j1; ++j) {
      ss += __half2float(tbuf[j * 132 + c]);
      const int dj = didx[j];
      if (j == j1 - 1 || didx[j + 1] != dj) {
        atomicAdd(&h_agg[(size_t)dj * CC + c], ss);
        ss = 0.0f;
      }
    }
  } else {
    // ---- m f16 back into ab (swizzled, A of GEMM3) -------------------------------------------
    #pragma unroll
    for (int mi = 0; mi < 8; ++mi) {
      #pragma unroll
      for (int r = 0; r < 4; ++r) {
        const int row = mi * 16 + quad * 4 + r;
        ab[row * 128 + (((c0 >> 3) ^ (row & 15)) * 8) + (c0 & 7)] = __float2half(mm[mi][r]);
      }
    }
    __syncthreads();
    // ---- segmented scan (reads swizzled ab) --------------------------------------------------
    {
      const int c = tid & 127, grp = tid >> 7;
      const int j0 = grp * 32, j1 = j0 + 32;
      float ss = 0.0f;
      for (int j = j0; j < j1; ++j) {
        ss += __half2float(ab[j * 128 + (((c >> 3) ^ (j & 15)) * 8) + (c & 7)]);
        const int dj = didx[j];
        if (j == j1 - 1 || didx[j + 1] != dj) {
          atomicAdd(&h_agg[(size_t)dj * CC + c], ss);
          ss = 0.0f;
        }
      }
    }
    // ---- GEMM3: m[128x128]@cw1, f16 -> silu -> t; cm = t . cw2; segmented x_agg flush --------
    f32x4 tt[8];
    {
      const float b0 = cb1[c0];
      #pragma unroll
      for (int mi = 0; mi < 8; ++mi) tt[mi] = (f32x4){b0, b0, b0, b0};
    }
    {
      const __half* bh0 = W3h + (size_t)c0 * 128 + quad * 8;
      const __half* bl0 = W3l + (size_t)c0 * 128 + quad * 8;
      #pragma unroll
      for (int ks = 0; ks < 4; ++ks) {
        const half8 Bh0 = *(const half8*)(bh0 + ks * 32);
        const half8 Bl0 = *(const half8*)(bl0 + ks * 32);
        #pragma unroll
        for (int mi = 0; mi < 8; ++mi) {
          const half8 A = *(const half8*)(ab + (mi * 16 + li) * 128 + (((ks * 4 + quad) ^ li) * 8));
          tt[mi] = mfma16f(A, Bh0, tt[mi]);
          tt[mi] = mfma16f(A, Bl0, tt[mi]);
        }
      }
    }
    __syncthreads();   // scan + GEMM3 reads of ab done before tbuf alias
    #pragma unroll
    for (int mi = 0; mi < 8; ++mi) {
      #pragma unroll
      for (int r = 0; r < 4; ++r)
        tbuf[(mi * 16 + quad * 4 + r) * 132 + c0] = __float2half(silu_f(tt[mi][r]));
    }
    __syncthreads();
    if (tid < EPB) {
      float ss = 0.0f;
      #pragma unroll 8
      for (int k = 0; k < CC; ++k) ss += __half2float(tbuf[tid * 132 + k]) * cw2s[k];
      sx[tid] = ss;
    }
    __syncthreads();
    if (tid < 12) {
      const int c = tid >> 2, grp = tid & 3;   // 3 ch x 4 groups of 32 rows
      const int j0 = grp * 32, j1 = j0 + 32;
      float a = 0.0f;
      for (int j = j0; j < j1; ++j) {
        a += sx[j] * xdn[j][c];
        const int dj = didx[j];
        if (j == j1 - 1 || didx[j + 1] != dj) {
          atomicAdd(&x_agg[(size_t)dj * 3 + c], a);
          a = 0.0f;
        }
      }
    }
  }
}

// ============================ node MFMA kernel (validated R14) ==================================
__global__ __launch_bounds__(256)
void node_mfma(const __half* __restrict__ h_hi, const __half* __restrict__ h_lo,
               const float* __restrict__ h_agg,
               const __half* __restrict__ NW1h, const __half* __restrict__ NW1l,
               const float* __restrict__ nb1,
               const __half* __restrict__ NW2h, const __half* __restrict__ NW2l,
               const float* __restrict__ nb2,
               __half* __restrict__ ho_hi, __half* __restrict__ ho_lo, const int post_ln,
               const float* __restrict__ lng, const float* __restrict__ lnb,
               const int do_coord, const float* __restrict__ xin,
               const float* __restrict__ x_agg, float* __restrict__ coord_out)
{
  __shared__ __align__(16) __half ab[32 * 256];
  __shared__ __align__(16) __half ab2[32 * 128];
  __shared__ float cbuf[32 * 132];

  const int tid = threadIdx.x;
  const int n0 = blockIdx.x * 32;

  {
    const int row = tid >> 3, q = tid & 7;
    int n = n0 + row; if (n >= NN) n = NN - 1;
    #pragma unroll
    for (int t = 0; t < 2; ++t) {
      const int c8 = q * 2 + t;
      const uint4 v = *(const uint4*)(h_hi + (size_t)n * CC + c8 * 8);
      *(uint4*)(ab + row * 256 + ((c8 ^ (row & 15)) * 8)) = v;
    }
    #pragma unroll
    for (int t = 0; t < 2; ++t) {
      const int c8 = 16 + q * 2 + t;
      const float4 a0 = *(const float4*)(h_agg + (size_t)n * CC + (q * 2 + t) * 8);
      const float4 a1 = *(const float4*)(h_agg + (size_t)n * CC + (q * 2 + t) * 8 + 4);
      uint4 H;
      H.x = pkrtz(a0.x, a0.y); H.y = pkrtz(a0.z, a0.w);
      H.z = pkrtz(a1.x, a1.y); H.w = pkrtz(a1.z, a1.w);
      *(uint4*)(ab + row * 256 + ((c8 ^ (row & 15)) * 8)) = H;
    }
  }
  if (do_coord && tid < 96) {
    const int n = n0 + tid / 3, d = tid % 3;
    if (n < NN)
      coord_out[(size_t)n * 3 + d] = xin[(size_t)n * 3 + d] + x_agg[(size_t)n * 3 + d];
  }
  __syncthreads();

  const int lane = tid & 63;
  const int li = lane & 15, quad = lane >> 4;
  const int wv = tid >> 6;

  f32x4 a1[2][2];
  {
    const float b0 = nb1[wv * 32 + li], b1 = nb1[wv * 32 + 16 + li];
    a1[0][0] = a1[1][0] = (f32x4){b0, b0, b0, b0};
    a1[0][1] = a1[1][1] = (f32x4){b1, b1, b1, b1};
  }
  {
    const __half* b0h = NW1h + (size_t)(wv * 32 + li) * 256 + quad * 8;
    const __half* b0l = NW1l + (size_t)(wv * 32 + li) * 256 + quad * 8;
    const __half* b1h = NW1h + (size_t)(wv * 32 + 16 + li) * 256 + quad * 8;
    const __half* b1l = NW1l + (size_t)(wv * 32 + 16 + li) * 256 + quad * 8;
    #pragma unroll
    for (int ks = 0; ks < 8; ++ks) {
      const half8 Bh0 = *(const half8*)(b0h + ks * 32);
      const half8 Bl0 = *(const half8*)(b0l + ks * 32);
      const half8 Bh1 = *(const half8*)(b1h + ks * 32);
      const half8 Bl1 = *(const half8*)(b1l + ks * 32);
      #pragma unroll
      for (int mi = 0; mi < 2; ++mi) {
        const half8 A = *(const half8*)(ab + (mi * 16 + li) * 256 + (((ks * 4 + quad) ^ li) * 8));
        a1[mi][0] = mfma16f(A, Bh0, a1[mi][0]);
        a1[mi][0] = mfma16f(A, Bl0, a1[mi][0]);
        a1[mi][1] = mfma16f(A, Bh1, a1[mi][1]);
        a1[mi][1] = mfma16f(A, Bl1, a1[mi][1]);
      }
    }
  }
  #pragma unroll
  for (int mi = 0; mi < 2; ++mi) {
    #pragma unroll
    for (int nc = 0; nc < 2; ++nc) {
      const int col = wv * 32 + nc * 16 + li;
      #pragma unroll
      for (int r = 0; r < 4; ++r) {
        const int row = mi * 16 + quad * 4 + r;
        ab2[row * 128 + (((col >> 3) ^ (row & 15)) * 8) + (col & 7)] =
            __float2half(silu_f(a1[mi][nc][r]));
      }
    }
  }
  __syncthreads();

  f32x4 a2[2][2];
  {
    const float b0 = nb2[wv * 32 + li], b1 = nb2[wv * 32 + 16 + li];
    a2[0][0] = a2[1][0] = (f32x4){b0, b0, b0, b0};
    a2[0][1] = a2[1][1] = (f32x4){b1, b1, b1, b1};
  }
  {
    const __half* b0h = NW2h + (size_t)(wv * 32 + li) * 128 + quad * 8;
    const __half* b0l = NW2l + (size_t)(wv * 32 + li) * 128 + quad * 8;
    const __half* b1h = NW2h + (size_t)(wv * 32 + 16 + li) * 128 + quad * 8;
    const __half* b1l = NW2l + (size_t)(wv * 32 + 16 + li) * 128 + quad * 8;
    #pragma unroll
    for (int ks = 0; ks < 4; ++ks) {
      const half8 Bh0 = *(const half8*)(b0h + ks * 32);
      const half8 Bl0 = *(const half8*)(b0l + ks * 32);
      const half8 Bh1 = *(const half8*)(b1h + ks * 32);
      const half8 Bl1 = *(const half8*)(b1l + ks * 32);
      #pragma unroll
      for (int mi = 0; mi < 2; ++mi) {
        const half8 A = *(const half8*)(ab2 + (mi * 16 + li) * 128 + (((ks * 4 + quad) ^ li) * 8));
        a2[mi][0] = mfma16f(A, Bh0, a2[mi][0]);
        a2[mi][0] = mfma16f(A, Bl0, a2[mi][0]);
        a2[mi][1] = mfma16f(A, Bh1, a2[mi][1]);
        a2[mi][1] = mfma16f(A, Bl1, a2[mi][1]);
      }
    }
  }
  #pragma unroll
  for (int mi = 0; mi < 2; ++mi) {
    #pragma unroll
    for (int nc = 0; nc < 2; ++nc) {
      const int col = wv * 32 + nc * 16 + li;
      #pragma unroll
      for (int r = 0; r < 4; ++r)
        cbuf[(mi * 16 + quad * 4 + r) * 132 + col] = a2[mi][nc][r];
    }
  }
  __syncthreads();

  {
    const int row = tid >> 3, q = tid & 7;
    const int n = n0 + row;
    float v[16];
    #pragma unroll
    for (int i = 0; i < 16; ++i) v[i] = cbuf[row * 132 + q * 16 + i];
    if (post_ln) {
      float s = 0.0f;
      #pragma unroll
      for (int i = 0; i < 16; ++i) { v[i] = gelu_f(v[i]); s += v[i]; }
      const float mu = hsum8(s) * (1.0f / 128.0f);
      float vs = 0.0f;
      #pragma unroll
      for (int i = 0; i < 16; ++i) { v[i] -= mu; vs += v[i] * v[i]; }
      const float rs = rsqrtf(hsum8(vs) * (1.0f / 128.0f) + 1e-5f);
      #pragma unroll
      for (int i = 0; i < 16; ++i)
        v[i] = v[i] * rs * lng[q * 16 + i] + lnb[q * 16 + i];
    }
    if (n < NN) {
      __half h[16], l[16];
      #pragma unroll
      for (int i = 0; i < 16; ++i) {
        h[i] = __float2half(v[i]);
        l[i] = __float2half(v[i] - __half2float(h[i]));
      }
      #pragma unroll
      for (int t = 0; t < 2; ++t) {
        *(uint4*)(ho_hi + (size_t)n * CC + q * 16 + t * 8) = *(uint4*)(h + t * 8);
        *(uint4*)(ho_lo + (size_t)n * CC + q * 16 + t * 8) = *(uint4*)(l + t * 8);
      }
    }
  }
}

// ============================ fp32 node-side kernels (embed / out) ==============================
template<int K, int ROWS>
__device__ __forceinline__ void mm_tile(const float* __restrict__ fb, const int fstride,
                                        const float* __restrict__ W, const float* __restrict__ bias,
                                        const int c0, const int r0, float (&acc)[ROWS][4])
{
  const float4 b = *(const float4*)(bias + c0);
  #pragma unroll
  for (int i = 0; i < ROWS; ++i) { acc[i][0] = b.x; acc[i][1] = b.y; acc[i][2] = b.z; acc[i][3] = b.w; }
  #pragma unroll 2
  for (int k = 0; k < K; k += 4) {
    const float4 w0 = *(const float4*)(W + (size_t)(k + 0) * CC + c0);
    const float4 w1 = *(const float4*)(W + (size_t)(k + 1) * CC + c0);
    const float4 w2 = *(const float4*)(W + (size_t)(k + 2) * CC + c0);
    const float4 w3 = *(const float4*)(W + (size_t)(k + 3) * CC + c0);
    #pragma unroll
    for (int i = 0; i < ROWS; ++i) {
      const float4 f = *(const float4*)(fb + (r0 + i) * fstride + k);
      acc[i][0] += f.x * w0.x + f.y * w1.x + f.z * w2.x + f.w * w3.x;
      acc[i][1] += f.x * w0.y + f.y * w1.y + f.z * w2.y + f.w * w3.y;
      acc[i][2] += f.x * w0.z + f.y * w1.z + f.z * w2.z + f.w * w3.z;
      acc[i][3] += f.x * w0.w + f.y * w1.w + f.z * w2.w + f.w * w3.w;
    }
  }
}

__device__ __forceinline__ void ln_then_gelu(float (&v)[4], const float* __restrict__ g,
                                             const float* __restrict__ b, const int c0)
{
  const float mu = hsum32(v[0] + v[1] + v[2] + v[3]) * (1.0f / 128.0f);
  const float d0 = v[0] - mu, d1 = v[1] - mu, d2 = v[2] - mu, d3 = v[3] - mu;
  const float var = hsum32(d0 * d0 + d1 * d1 + d2 * d2 + d3 * d3) * (1.0f / 128.0f);
  const float rs = rsqrtf(var + 1e-5f);
  const float4 gv = *(const float4*)(g + c0);
  const float4 bv = *(const float4*)(b + c0);
  v[0] = gelu_f(d0 * rs * gv.x + bv.x);
  v[1] = gelu_f(d1 * rs * gv.y + bv.y);
  v[2] = gelu_f(d2 * rs * gv.z + bv.z);
  v[3] = gelu_f(d3 * rs * gv.w + bv.w);
}

__device__ __forceinline__ void store_hilo4(__half* __restrict__ hi, __half* __restrict__ lo,
                                            const float v0, const float v1,
                                            const float v2, const float v3)
{
  __half h[4], l[4];
  h[0] = __float2half(v0); h[1] = __float2half(v1); h[2] = __float2half(v2); h[3] = __float2half(v3);
  l[0] = __float2half(v0 - __half2float(h[0]));
  l[1] = __float2half(v1 - __half2float(h[1]));
  l[2] = __float2half(v2 - __half2float(h[2]));
  l[3] = __float2half(v3 - __half2float(h[3]));
  *(ushort4*)hi = *(ushort4*)h;
  *(ushort4*)lo = *(ushort4*)l;
}

__global__ __launch_bounds__(256)
void embed_kernel(const float* __restrict__ na,
                  const float* __restrict__ w1, const float* __restrict__ b1,
                  const float* __restrict__ g1, const float* __restrict__ be1,
                  const float* __restrict__ w2, const float* __restrict__ b2,
                  const float* __restrict__ g2, const float* __restrict__ be2,
                  __half* __restrict__ ho_hi, __half* __restrict__ ho_lo)
{
  const int AS = 68, MS = 132;
  __shared__ float ain[16 * AS];
  __shared__ float hb[16 * MS];
  const int tid = threadIdx.x;
  const size_t n0 = (size_t)blockIdx.x * 16;
  {
    const int n = tid >> 4, q = tid & 15;
    *(float4*)(ain + n * AS + q * 4) = *(const float4*)(na + (n0 + n) * FIN + q * 4);
  }
  __syncthreads();
  const int cg = tid & 31, ng = tid >> 5;
  const int c0 = cg * 4, m0 = ng * 2;
  float acc[2][4];
  mm_tile<64, 2>(ain, AS, w1, b1, c0, m0, acc);
  #pragma unroll
  for (int i = 0; i < 2; ++i) {
    ln_then_gelu(acc[i], g1, be1, c0);
    *(float4*)(hb + (m0 + i) * MS + c0) = make_float4(acc[i][0], acc[i][1], acc[i][2], acc[i][3]);
  }
  __syncthreads();
  float acc2[2][4];
  mm_tile<128, 2>(hb, MS, w2, b2, c0, m0, acc2);
  #pragma unroll
  for (int i = 0; i < 2; ++i) {
    ln_then_gelu(acc2[i], g2, be2, c0);
    store_hilo4(ho_hi + (n0 + m0 + i) * CC + c0, ho_lo + (n0 + m0 + i) * CC + c0,
                acc2[i][0], acc2[i][1], acc2[i][2], acc2[i][3]);
  }
}

__global__ __launch_bounds__(192)
void out_kernel(const __half* __restrict__ h_hi, const __half* __restrict__ h_lo,
                const float* __restrict__ w, const float* __restrict__ b,
                float* __restrict__ out)
{
  const int gid = blockIdx.x * 192 + threadIdx.x;
  if (gid >= NN * 3) return;
  const int n = gid / 3, j = gid % 3;
  float acc = b[j];
  const __half* hh = h_hi + (size_t)n * CC;
  const __half* hl = h_lo + (size_t)n * CC;
  #pragma unroll 4
  for (int k = 0; k < CC; ++k) acc += (__half2float(hh[k]) + __half2float(hl[k])) * w[k * 3 + j];
  out[gid] = acc;
}

// ================================================================================================
extern "C" void kernel_launch(void* const* d_in, const int* in_sizes, int n_in,
                              void* d_out, int out_size, void* d_ws, size_t ws_size,
                              hipStream_t stream)
{
  (void)in_sizes; (void)n_in; (void)out_size; (void)ws_size;
  const int*   src       = (const int*)d_in[0];
  const int*   dst       = (const int*)d_in[1];
  const float* node_attr = (const float*)d_in[2];
  const float* xyz       = (const float*)d_in[3];
  const float* emb_w1    = (const float*)d_in[4];
  const float* emb_b1    = (const float*)d_in[5];
  const float* ln1_g     = (const float*)d_in[6];
  const float* ln1_b     = (const float*)d_in[7];
  const float* emb_w2    = (const float*)d_in[8];
  const float* emb_b2    = (const float*)d_in[9];
  const float* ln2_g     = (const float*)d_in[10];
  const float* ln2_b     = (const float*)d_in[11];
  const float* e_w1      = (const float*)d_in[12];
  const float* e_b1      = (const float*)d_in[13];
  const float* e_w2      = (const float*)d_in[14];
  const float* e_b2      = (const float*)d_in[15];
  const float* n_w1      = (const float*)d_in[16];
  const float* n_b1      = (const float*)d_in[17];
  const float* n_w2      = (const float*)d_in[18];
  const float* n_b2      = (const float*)d_in[19];
  const float* c_w1      = (const float*)d_in[20];
  const float* c_b1      = (const float*)d_in[21];
  const float* c_w2      = (const float*)d_in[22];
  const float* dec_ln_g  = (const float*)d_in[23];
  const float* dec_ln_b  = (const float*)d_in[24];
  const float* out_w     = (const float*)d_in[25];
  const float* out_b     = (const float*)d_in[26];

  // workspace layout (~95 MB total)
  char* wsb = (char*)d_ws;
  float*  h_agg = (float*)wsb;                      wsb += (size_t)NN * CC * 4;   // 25.6 MB
  __half* PQ    = (__half*)wsb;                     wsb += (size_t)NN * 256 * 2;  // 25.6 MB
  float*  x_agg = (float*)wsb;                      wsb += (size_t)NN * 3 * 4;
  float*  coord = (float*)wsb;                      wsb += (size_t)NN * 3 * 4;
  __half* h_hi  = (__half*)wsb;                     wsb += (size_t)NN * CC * 2;   // 12.8 MB
  __half* h_lo  = (__half*)wsb;                     wsb += (size_t)NN * CC * 2;   // 12.8 MB
  __half* W1h   = (__half*)wsb;                     wsb += (size_t)3 * 128 * 256 * 2;
  __half* W1l   = (__half*)wsb;                     wsb += (size_t)3 * 128 * 256 * 2;
  __half* W2h   = (__half*)wsb;                     wsb += (size_t)3 * 128 * 128 * 2;
  __half* W2l   = (__half*)wsb;                     wsb += (size_t)3 * 128 * 128 * 2;
  __half* W3h   = (__half*)wsb;                     wsb += (size_t)128 * 128 * 2;
  __half* W3l   = (__half*)wsb;                     wsb += (size_t)128 * 128 * 2;
  __half* NW1h  = (__half*)wsb;                     wsb += (size_t)3 * 128 * 256 * 2;
  __half* NW1l  = (__half*)wsb;                     wsb += (size_t)3 * 128 * 256 * 2;
  __half* NW2h  = (__half*)wsb;                     wsb += (size_t)3 * 128 * 128 * 2;
  __half* NW2l  = (__half*)wsb;                     wsb += (size_t)3 * 128 * 128 * 2;
  int2*   sdA   = (int2*)wsb;                       wsb += (size_t)NE * 8;        // 12.8 MB
  int*    cnt   = (int*)wsb;                        wsb += (size_t)NN * 4;
  int*    nextA = (int*)wsb;                        wsb += (size_t)NN * 4;
  float*  out   = (float*)d_out;

  const int NGRID = NN / 16;            // 3125 (embed)
  const int N32GRID = (NN + 31) / 32;   // 1563 (node_mfma / pq)
  const int EGRID = NE / 128;           // 12500 (128 edges/block)

  // weight split (tiny)
  wt_split<<<(3 * 128 * 256 + 255) / 256, 256, 0, stream>>>(e_w1, W1h, W1l, 256, 3, 257 * 128);
  wt_split<<<(3 * 128 * 128 + 255) / 256, 256, 0, stream>>>(e_w2, W2h, W2l, 128, 3, 128 * 128);
  wt_split<<<(128 * 128 + 255) / 256, 256, 0, stream>>>(c_w1 + (size_t)128 * 128, W3h, W3l, 128, 1, 0);
  wt_split<<<(3 * 128 * 256 + 255) / 256, 256, 0, stream>>>(n_w1, NW1h, NW1l, 256, 3, 256 * 128);
  wt_split<<<(3 * 128 * 128 + 255) / 256, 256, 0, stream>>>(n_w2, NW2h, NW2l, 128, 3, 128 * 128);

  // dst-sort (counting sort) once per call; sorted (src,dst) pairs written directly
  (void)hipMemsetAsync(cnt, 0, (size_t)NN * 4, stream);
  hist_kernel<<<(NE + 255) / 256, 256, 0, stream>>>(dst, cnt);
  scan_kernel<<<1, 1024, 0, stream>>>(cnt, nextA);
  slot_kernel<<<(NE + 255) / 256, 256, 0, stream>>>(src, dst, nextA, sdA);

  embed_kernel<<<NGRID, 256, 0, stream>>>(node_attr, emb_w1, emb_b1, ln1_g, ln1_b,
                                          emb_w2, emb_b2, ln2_g, ln2_b, h_hi, h_lo);

  // ---- layer 0 (encoder): coord output discarded
  (void)hipMemsetAsync(h_agg, 0, (size_t)NN * CC * 4, stream);
  pq_kernel<<<N32GRID, 256, 0, stream>>>(h_hi, W1h, W1l, e_b1, PQ);
  edge_kernel<0><<<EGRID, 512, 0, stream>>>(sdA, PQ, xyz,
      e_w1 + (size_t)256 * CC, W2h, W2l, e_b2, W3h, W3l, c_b1, c_w2, h_agg, x_agg);
  node_mfma<<<N32GRID, 256, 0, stream>>>(h_hi, h_lo, h_agg,
      NW1h, NW1l, n_b1, NW2h, NW2l, n_b2,
      h_hi, h_lo, 0, dec_ln_g, dec_ln_b, 0, xyz, x_agg, coord);

  // ---- layer 1 (decoder #1): coord MLP active; input coords = xyz
  (void)hipMemsetAsync(h_agg, 0, (size_t)NN * CC * 4, stream);
  (void)hipMemsetAsync(x_agg, 0, (size_t)NN * 3 * 4, stream);
  pq_kernel<<<N32GRID, 256, 0, stream>>>(h_hi, W1h + (size_t)128 * 256,
      W1l + (size_t)128 * 256, e_b1 + CC, PQ);
  edge_kernel<1><<<EGRID, 512, 0, stream>>>(sdA, PQ, xyz,
      e_w1 + (size_t)(257 + 256) * CC,
      W2h + (size_t)128 * 128, W2l + (size_t)128 * 128, e_b2 + CC,
      W3h, W3l, c_b1 + CC, c_w2 + CC, h_agg, x_agg);
  node_mfma<<<N32GRID, 256, 0, stream>>>(h_hi, h_lo, h_agg,
      NW1h + (size_t)128 * 256, NW1l + (size_t)128 * 256, n_b1 + CC,
      NW2h + (size_t)128 * 128, NW2l + (size_t)128 * 128, n_b2 + CC,
      h_hi, h_lo, 1, dec_ln_g, dec_ln_b, 1, xyz, x_agg, coord);

  // ---- layer 2 (decoder #2): coord output discarded; input coords = coord
  (void)hipMemsetAsync(h_agg, 0, (size_t)NN * CC * 4, stream);
  pq_kernel<<<N32GRID, 256, 0, stream>>>(h_hi, W1h + (size_t)2 * 128 * 256,
      W1l + (size_t)2 * 128 * 256, e_b1 + 2 * CC, PQ);
  edge_kernel<0><<<EGRID, 512, 0, stream>>>(sdA, PQ, coord,
      e_w1 + (size_t)(2 * 257 + 256) * CC,
      W2h + (size_t)2 * 128 * 128, W2l + (size_t)2 * 128 * 128, e_b2 + 2 * CC,
      W3h, W3l, c_b1, c_w2, h_agg, x_agg);
  node_mfma<<<N32GRID, 256, 0, stream>>>(h_hi, h_lo, h_agg,
      NW1h + (size_t)2 * 128 * 256, NW1l + (size_t)2 * 128 * 256, n_b1 + 2 * CC,
      NW2h + (size_t)2 * 128 * 128, NW2l + (size_t)2 * 128 * 128, n_b2 + 2 * CC,
      h_hi, h_lo, 1, dec_ln_g, dec_ln_b, 0, xyz, x_agg, coord);

  out_kernel<<<(NN * 3 + 191) / 192, 192, 0, stream>>>(h_hi, h_lo, out_w, out_b, out);
}